// Round 8
// baseline (1633.085 us; speedup 1.0000x reference)
//
#include <hip/hip_runtime.h>
#include <hip/hip_bf16.h>
#include <math.h>

#define NF 128
#define EC 50
#define ET 64              // edges per seg_conv tile
#define CUTOFF 0.8f
#define PI_F 3.14159265358979323846f

typedef __attribute__((ext_vector_type(8))) _Float16 f16x8;
typedef __attribute__((ext_vector_type(2))) _Float16 f16x2;
typedef __attribute__((ext_vector_type(4))) float f32x4;

__device__ __forceinline__ float4 ld4(const float* p) { return *reinterpret_cast<const float4*>(p); }
__device__ __forceinline__ void st4(float* p, float4 v) { *reinterpret_cast<float4*>(p) = v; }

__device__ __forceinline__ float4 f4fma(float a, float4 w, float4 acc) {
    acc.x = fmaf(a, w.x, acc.x); acc.y = fmaf(a, w.y, acc.y);
    acc.z = fmaf(a, w.z, acc.z); acc.w = fmaf(a, w.w, acc.w);
    return acc;
}

// fast ssp: hardware exp/log; abs err ~1e-7 (validated R7, absmax 0.0078)
__device__ __forceinline__ float sspf(float x) {
    return fmaxf(x, 0.0f) + __logf(1.0f + __expf(-fabsf(x))) - 0.69314718055994530942f;
}
__device__ __forceinline__ float4 ssp4(float4 v) {
    v.x = sspf(v.x); v.y = sspf(v.y); v.z = sspf(v.z); v.w = sspf(v.w);
    return v;
}
__device__ __forceinline__ float swishf(float x) {
    return x / (1.0f + __expf(-x));
}

// -------------------------------------------------------------------------
__global__ __launch_bounds__(256) void emb_kernel(const float* __restrict__ tt,
                                                  float* __restrict__ emb, int n) {
    int i = blockIdx.x * blockDim.x + threadIdx.x;
    if (i >= n * 64) return;
    int node = i >> 6, k = i & 63;
    float t = tt[node];
    float coef = __expf((float)k * (-6.9077552789821368f / 63.0f));
    float e = t * coef;
    emb[node * NF + k]      = swishf(__sinf(e));
    emb[node * NF + 64 + k] = swishf(__cosf(e));
}

// -------------------------------------------------------------------------
// out[N,128] = f(A[N,128] @ W[128,128] (+bias) (+extra))
// MODE 0: plain. MODE 1: ssp(.+b). MODE 2: ssp(.+b+extra). MODE 3: .+b
// W read from global (L1/L2 broadcast; R2-validated). A staged in LDS (16 KB).
// In-place safety: A==out safe (A staged to LDS before stores); extra==out
// safe (each element read by its writing thread before the write).
template<int MODE>
__global__ __launch_bounds__(256, 6) void node_gemm(const float* A,
                                                    const float* __restrict__ W,
                                                    const float* __restrict__ bias,
                                                    const float* extra,
                                                    float* out, int n) {
    __shared__ __align__(16) float A_lds[32 * NF];
    const int tid = threadIdx.x;
    const int cg = tid & 31;
    const int rg = tid >> 5;

    float4 bv = make_float4(0.f, 0.f, 0.f, 0.f);
    if (MODE != 0) bv = ld4(bias + 4 * cg);

    const int ntile = (n + 31) >> 5;
    for (int tile = blockIdx.x; tile < ntile; tile += gridDim.x) {
        const int base = tile << 5;
        __syncthreads();
        for (int idx = tid * 4; idx < 32 * NF; idx += 1024) {
            int r = idx >> 7;
            int row = base + r;
            float4 v = make_float4(0.f, 0.f, 0.f, 0.f);
            if (row < n) v = ld4(A + row * NF + (idx & 127));
            st4(A_lds + idx, v);
        }
        __syncthreads();

        float4 acc[4] = {bv, bv, bv, bv};
        #pragma unroll 8
        for (int k4 = 0; k4 < 32; k4++) {
            float4 w0 = ld4(W + (4 * k4 + 0) * NF + 4 * cg);
            float4 w1 = ld4(W + (4 * k4 + 1) * NF + 4 * cg);
            float4 w2 = ld4(W + (4 * k4 + 2) * NF + 4 * cg);
            float4 w3 = ld4(W + (4 * k4 + 3) * NF + 4 * cg);
            #pragma unroll
            for (int rr = 0; rr < 4; rr++) {
                float4 a = ld4(A_lds + (rg * 4 + rr) * NF + 4 * k4);
                acc[rr] = f4fma(a.x, w0, acc[rr]);
                acc[rr] = f4fma(a.y, w1, acc[rr]);
                acc[rr] = f4fma(a.z, w2, acc[rr]);
                acc[rr] = f4fma(a.w, w3, acc[rr]);
            }
        }
        #pragma unroll
        for (int rr = 0; rr < 4; rr++) {
            int row = base + rg * 4 + rr;
            if (row >= n) continue;
            float4 v = acc[rr];
            if (MODE == 2) {
                float4 e4 = ld4(extra + row * NF + 4 * cg);
                v.x += e4.x; v.y += e4.y; v.z += e4.z; v.w += e4.w;
            }
            if (MODE == 1 || MODE == 2) v = ssp4(v);
            st4(out + row * NF + 4 * cg, v);
        }
    }
}

// -------------------------------------------------------------------------
// CSR build; scatter also emits conv-invariant srcp/dstp/Cp in sorted order.
__global__ __launch_bounds__(256) void deg_kernel(const int* __restrict__ ei,
                                                  int* __restrict__ deg, int E_) {
    int e = blockIdx.x * blockDim.x + threadIdx.x;
    if (e < E_) atomicAdd(&deg[ei[E_ + e]], 1);
}

__global__ __launch_bounds__(1024) void scan_kernel(const int* __restrict__ deg,
                                                    int* __restrict__ off, int n) {
    __shared__ int sm[1024];
    __shared__ int carry_s;
    const int tid = threadIdx.x;
    if (tid == 0) carry_s = 0;
    __syncthreads();
    for (int base = 0; base < n; base += 1024) {
        int v = (base + tid < n) ? deg[base + tid] : 0;
        sm[tid] = v;
        __syncthreads();
        for (int s = 1; s < 1024; s <<= 1) {
            int t = (tid >= s) ? sm[tid - s] : 0;
            __syncthreads();
            sm[tid] += t;
            __syncthreads();
        }
        int carry = carry_s;
        if (base + tid < n) off[base + tid] = carry + sm[tid] - v;  // exclusive
        __syncthreads();
        if (tid == 0) carry_s = carry + sm[1023];
        __syncthreads();
    }
    if (tid == 0) off[n] = carry_s;
}

__global__ __launch_bounds__(256) void scatter_kernel(const int* __restrict__ ei,
                                                      const float* __restrict__ elen,
                                                      const int* __restrict__ off,
                                                      int* __restrict__ cur,
                                                      int* __restrict__ perm,
                                                      int* __restrict__ srcp,
                                                      int* __restrict__ dstp,
                                                      float* __restrict__ Cp, int E_) {
    int e = blockIdx.x * blockDim.x + threadIdx.x;
    if (e < E_) {
        int d = ei[E_ + e];
        int p = off[d] + atomicAdd(&cur[d], 1);
        perm[p] = e;
        srcp[p] = ei[e];
        dstp[p] = d;
        float len = elen[e];
        float c = 0.5f * (__cosf(len * (PI_F / CUTOFF)) + 1.0f);
        Cp[p] = (len <= CUTOFF && len >= 0.0f) ? c : 0.0f;
    }
}

// -------------------------------------------------------------------------
// Edge-centric cfconv over dst-sorted edges, 64-edge dense MFMA tiles,
// fp16 msg + (channel-pair x edge-quarter) segmented reduce.
// LDS ~24.8 KB -> 6 blocks/CU.
__global__ __launch_bounds__(256, 6) void seg_conv(const float* __restrict__ y,
                                                   const float* __restrict__ eattr,
                                                   const float* __restrict__ em1w,
                                                   const float* __restrict__ em1b,
                                                   const float* __restrict__ em2w,
                                                   const float* __restrict__ em2b,
                                                   const int* __restrict__ perm,
                                                   const int* __restrict__ srcp,
                                                   const int* __restrict__ dstp,
                                                   const float* __restrict__ Cp,
                                                   float* __restrict__ agg,
                                                   int E_) {
    // union: [ea 8KB | h 16KB] = 24KB, overlapped by msg fp16 [64][132] (16.9KB)
    __shared__ __align__(16) char U[ET * 128 + ET * 256];
    __shared__ float C_sm[ET];
    __shared__ int ssm[ET];
    __shared__ int ddm[ET];
    char* ea_p  = U;               // [64][64k] fp16 swizzled
    char* h_p   = U + ET * 128;    // [64][128ch] fp16 swizzled
    char* msg_b = U;               // [64] rows x 264B (132 fp16)

    const int tid  = threadIdx.x;
    const int wid  = tid >> 6;
    const int lane = tid & 63;
    const int l15  = lane & 15;
    const int lhi  = lane >> 4;

    // ---- preload weight B-frags (R3-verified layout)
    f16x8 w1f[2][2];
    f16x8 w2f[2][4];
    float b1c[2], b2c[2];
    #pragma unroll
    for (int ct = 0; ct < 2; ct++) {
        const int col = (2 * wid + ct) * 16 + l15;
        b1c[ct] = em1b[col];
        b2c[ct] = em2b[col];
        #pragma unroll
        for (int t = 0; t < 2; t++)
            #pragma unroll
            for (int j = 0; j < 8; j++) {
                int k = t * 32 + lhi * 8 + j;
                w1f[ct][t][j] = (_Float16)((k < EC) ? em1w[k * NF + col] : 0.0f);
            }
        #pragma unroll
        for (int t = 0; t < 4; t++)
            #pragma unroll
            for (int j = 0; j < 8; j++) {
                int k = t * 32 + lhi * 8 + j;
                w2f[ct][t][j] = (_Float16)em2w[k * NF + col];
            }
    }

    const int ntiles = (E_ + ET - 1) / ET;
    for (int tile = blockIdx.x; tile < ntiles; tile += gridDim.x) {
        const int base = tile * ET;
        __syncthreads();   // prev reduce done; safe to overwrite U/meta

        // ---- meta: coalesced conv-invariant streams (pads: 0/0/0)
        if (tid < ET) {
            int ii = base + tid;
            float Cv = 0.0f; int s = 0, d = 0;
            if (ii < E_) { Cv = Cp[ii]; s = srcp[ii]; d = dstp[ii]; }
            C_sm[tid] = Cv; ssm[tid] = s; ddm[tid] = d;
        }
        // ---- stage ea: thread -> (row = tid>>2, 16 k's); float2 loads
        {
            int row = tid >> 2, part = tid & 3;
            int ii = base + row;
            bool val = ii < E_;
            const float* ep = eattr + (size_t)(val ? perm[ii] : 0) * EC;
            #pragma unroll
            for (int kk = 0; kk < 16; kk += 2) {
                int k = part * 16 + kk;
                float2 v = make_float2(0.f, 0.f);
                if (val && k <= 48) v = *(const float2*)(ep + k);
                f16x2 p;
                p[0] = (_Float16)v.x; p[1] = (_Float16)v.y;
                *(f16x2*)(ea_p + row * 128 + ((2 * k) ^ ((row & 7) << 4))) = p;
            }
        }
        __syncthreads();

        // ---- layer 1: h = ssp(ea @ em1 + b1)
        f32x4 acc[4][2];
        #pragma unroll
        for (int m = 0; m < 4; m++)
            #pragma unroll
            for (int ct = 0; ct < 2; ct++) {
                f32x4 b = {b1c[ct], b1c[ct], b1c[ct], b1c[ct]};
                acc[m][ct] = b;
            }
        #pragma unroll
        for (int m = 0; m < 4; m++) {
            const int row = m * 16 + l15;
            #pragma unroll
            for (int t1 = 0; t1 < 2; t1++) {
                int o = row * 128 + ((t1 * 64 + lhi * 16) ^ ((row & 7) << 4));
                f16x8 a = *(const f16x8*)(ea_p + o);
                #pragma unroll
                for (int ct = 0; ct < 2; ct++)
                    acc[m][ct] = __builtin_amdgcn_mfma_f32_16x16x32_f16(a, w1f[ct][t1], acc[m][ct], 0, 0, 0);
            }
        }
        #pragma unroll
        for (int m = 0; m < 4; m++)
            #pragma unroll
            for (int ct = 0; ct < 2; ct++) {
                const int col = (2 * wid + ct) * 16 + l15;
                #pragma unroll
                for (int r = 0; r < 4; r++) {
                    int row = m * 16 + lhi * 4 + r;
                    *(_Float16*)(h_p + row * 256 + ((2 * col) ^ ((row & 7) << 4))) =
                        (_Float16)sspf(acc[m][ct][r]);
                }
            }
        __syncthreads();

        // ---- layer 2: wf = h @ em2 + b2
        #pragma unroll
        for (int m = 0; m < 4; m++)
            #pragma unroll
            for (int ct = 0; ct < 2; ct++) {
                f32x4 b = {b2c[ct], b2c[ct], b2c[ct], b2c[ct]};
                acc[m][ct] = b;
            }
        #pragma unroll
        for (int m = 0; m < 4; m++) {
            const int row = m * 16 + l15;
            #pragma unroll
            for (int t2 = 0; t2 < 4; t2++) {
                int o = row * 256 + ((t2 * 64 + lhi * 16) ^ ((row & 7) << 4));
                f16x8 a = *(const f16x8*)(h_p + o);
                #pragma unroll
                for (int ct = 0; ct < 2; ct++)
                    acc[m][ct] = __builtin_amdgcn_mfma_f32_16x16x32_f16(a, w2f[ct][t2], acc[m][ct], 0, 0, 0);
            }
        }
        __syncthreads();   // all h reads done; msg may overwrite ea/h

        // ---- msg[e][ch] = (fp16)(wf * C); row stride 264B (2-way, free)
        #pragma unroll
        for (int m = 0; m < 4; m++)
            #pragma unroll
            for (int ct = 0; ct < 2; ct++) {
                #pragma unroll
                for (int r = 0; r < 4; r++) {
                    int e = m * 16 + lhi * 4 + r;
                    int ch = (2 * wid + ct) * 16 + l15;
                    *(_Float16*)(msg_b + e * 264 + 2 * ch) =
                        (_Float16)(acc[m][ct][r] * C_sm[e]);
                }
            }
        __syncthreads();

        // ---- segmented reduce: thread = (channel pair c2, 16-edge quarter q)
        {
            int c2 = (tid & 63) * 2;   // wave lanes cover 128 ch as 64 pairs
            int q  = wid;              // quarter = wave id
            float a0 = 0.0f, a1 = 0.0f;
            int prev = ddm[q * 16];
            #pragma unroll
            for (int k = 0; k < 16; k++) {
                int e = q * 16 + k;
                f16x2 mp = *(const f16x2*)(msg_b + e * 264 + 2 * c2);
                float2 yv = *(const float2*)(y + (size_t)ssm[e] * NF + c2);
                int d = ddm[e];
                if (d != prev) {
                    unsafeAtomicAdd(agg + (size_t)prev * NF + c2, a0);
                    unsafeAtomicAdd(agg + (size_t)prev * NF + c2 + 1, a1);
                    a0 = 0.0f; a1 = 0.0f; prev = d;
                }
                a0 = fmaf((float)mp[0], yv.x, a0);
                a1 = fmaf((float)mp[1], yv.y, a1);
            }
            unsafeAtomicAdd(agg + (size_t)prev * NF + c2, a0);
            unsafeAtomicAdd(agg + (size_t)prev * NF + c2 + 1, a1);
        }
    }
}

// -------------------------------------------------------------------------
extern "C" void kernel_launch(void* const* d_in, const int* in_sizes, int n_in,
                              void* d_out, int out_size, void* d_ws, size_t ws_size,
                              hipStream_t stream) {
    const float* tt    = (const float*)d_in[0];
    const float* xx    = (const float*)d_in[1];
    const int*   ei    = (const int*)d_in[2];
    const float* elen  = (const float*)d_in[3];
    const float* eattr = (const float*)d_in[4];
    const float* em1w  = (const float*)d_in[5];
    const float* em1b  = (const float*)d_in[6];
    const float* em2w  = (const float*)d_in[7];
    const float* em2b  = (const float*)d_in[8];
    const float* c1m1w = (const float*)d_in[9];
    const float* c1m2w = (const float*)d_in[10];
    const float* c1m2b = (const float*)d_in[11];
    const float* c2m1w = (const float*)d_in[12];
    const float* c2m2w = (const float*)d_in[13];
    const float* c2m2b = (const float*)d_in[14];
    const float* tew   = (const float*)d_in[15];
    const float* teb   = (const float*)d_in[16];
    const float* linw  = (const float*)d_in[17];
    const float* linb  = (const float*)d_in[18];

    const int n  = in_sizes[0];
    const int E_ = in_sizes[2] / 2;
    float* out = (float*)d_out;

    // ws: B0,B1,B2 (3*NB floats) + CSR ints + srcp/dstp/Cp (~87 MB total,
    // within the 102.4 MB footprint proven in R1-R3). No d_out aliasing.
    const size_t NB = (size_t)n * NF;
    float* B0 = (float*)d_ws;   // y1 / y2 / x3
    float* B1 = B0 + NB;        // agg
    float* B2 = B1 + NB;        // emb -> t (in-place) -> x_mid
    int* off  = (int*)(B2 + NB);
    int* perm = off + (n + 1);
    int* deg  = perm + E_;
    int* cur  = deg + n;
    int* srcp = cur + n;
    int* dstp = srcp + E_;
    float* Cp = (float*)(dstp + E_);

    // ---- CSR build (shared by both convs)
    hipMemsetAsync(deg, 0, (size_t)2 * n * sizeof(int), stream);
    deg_kernel<<<(E_ + 255) / 256, 256, 0, stream>>>(ei, deg, E_);
    scan_kernel<<<1, 1024, 0, stream>>>(deg, off, n);
    scatter_kernel<<<(E_ + 255) / 256, 256, 0, stream>>>(ei, elen, off, cur,
                                                         perm, srcp, dstp, Cp, E_);

    // emb -> B2 ; t = swish_emb @ te_w + te_b -> B2 (in-place safe)
    emb_kernel<<<(n * 64 + 255) / 256, 256, 0, stream>>>(tt, B2, n);
    node_gemm<3><<<1024, 256, 0, stream>>>(B2, tew, teb, nullptr, B2, n);

    // y1 = xx @ c1_m1w -> B0
    node_gemm<0><<<1024, 256, 0, stream>>>(xx, c1m1w, nullptr, nullptr, B0, n);

    // conv1 -> B1 (atomic-accumulated; zero first)
    hipMemsetAsync(B1, 0, NB * sizeof(float), stream);
    seg_conv<<<1536, 256, 0, stream>>>(B0, eattr, em1w, em1b, em2w, em2b,
                                       perm, srcp, dstp, Cp, B1, E_);

    // x_mid = ssp(agg @ c1_m2w + b + t) -> B2 (extra==out elementwise-safe)
    node_gemm<2><<<1024, 256, 0, stream>>>(B1, c1m2w, c1m2b, B2, B2, n);

    // y2 = x_mid @ c2_m1w -> B0
    node_gemm<0><<<1024, 256, 0, stream>>>(B2, c2m1w, nullptr, nullptr, B0, n);

    // conv2 -> B1
    hipMemsetAsync(B1, 0, NB * sizeof(float), stream);
    seg_conv<<<1536, 256, 0, stream>>>(B0, eattr, em1w, em1b, em2w, em2b,
                                       perm, srcp, dstp, Cp, B1, E_);

    // x3 = ssp(agg @ c2_m2w + b) -> B0 ; out = ssp(x3 @ lin_w + b) -> d_out
    node_gemm<1><<<1024, 256, 0, stream>>>(B1, c2m2w, c2m2b, nullptr, B0, n);
    node_gemm<1><<<1024, 256, 0, stream>>>(B0, linw, linb, nullptr, out, n);
}